// Round 4
// baseline (72.970 us; speedup 1.0000x reference)
//
#include <hip/hip_runtime.h>
#include <math.h>

// Problem constants (fixed by the reference)
#define B_ 512
#define K_ 1024
#define D_ 256
#define EPS_ 1e-6f

typedef unsigned short u16;
using bf16x8 = __attribute__((ext_vector_type(8))) short;  // 8 bf16 = 4 VGPRs
using f32x4  = __attribute__((ext_vector_type(4))) float;  // MFMA C/D

// ---- workspace layout (u16 element offsets for the bf16 hi/lo arrays) ----
#define XHI_OFF 0
#define XLO_OFF (512 * 256)
#define PHI_OFF (2 * 512 * 256)
#define PLO_OFF (PHI_OFF + 1024 * 256)
#define AHI_OFF (PLO_OFF + 1024 * 256)
#define ALO_OFF (AHI_OFF + 1024 * 256)
#define BF16_TOTAL (ALO_OFF + 1024 * 256)      // 1,310,720 u16 = 2,621,440 B
#define SCAL_BYTE_OFF (BF16_TOTAL * 2)
// scalar floats at SCAL_BYTE_OFF: x2[512], p2[1024], a2[1024], pa[1024]

// round-to-nearest-even fp32 -> bf16, and the exact residual split
__device__ inline u16 bf16_rn(float v) {
    unsigned u = __float_as_uint(v);
    unsigned r = u + 0x7FFFu + ((u >> 16) & 1u);
    return (u16)(r >> 16);
}
__device__ inline void split2(float v, u16& h, u16& l) {
    h = bf16_rn(v);
    float hf = __uint_as_float(((unsigned)h) << 16);
    l = bf16_rn(v - hf);   // v - hf is exact (Sterbenz)
}

// ---------------------------------------------------------------------------
// Kernel 1: fp32 -> (hi, lo) bf16 conversion + per-row scalars.
// One wave per row; lane l owns elements [4l, 4l+4). Rows 0..511 = x,
// rows 512..1535 = (p, a) pairs. Grid 384 x 256 threads (4 rows/block).
// ---------------------------------------------------------------------------
__global__ __launch_bounds__(256) void prep_kernel(
    const float* __restrict__ x, const float* __restrict__ p,
    const float* __restrict__ a, u16* __restrict__ wsu,
    float* __restrict__ scal)
{
    const int lane = threadIdx.x & 63;
    const int rid  = blockIdx.x * 4 + (threadIdx.x >> 6);
    float* x2 = scal;
    float* p2 = scal + 512;
    float* a2 = scal + 512 + 1024;
    float* pa = scal + 512 + 2048;

    if (rid < 512) {
        const float4 v = *(const float4*)&x[rid * D_ + lane * 4];
        ushort4 h, l;
        split2(v.x, h.x, l.x); split2(v.y, h.y, l.y);
        split2(v.z, h.z, l.z); split2(v.w, h.w, l.w);
        *(ushort4*)&wsu[XHI_OFF + rid * D_ + lane * 4] = h;
        *(ushort4*)&wsu[XLO_OFF + rid * D_ + lane * 4] = l;
        float s = v.x * v.x + v.y * v.y + v.z * v.z + v.w * v.w;
#pragma unroll
        for (int off = 32; off; off >>= 1) s += __shfl_down(s, off);
        if (lane == 0) x2[rid] = s;
    } else {
        const int k = rid - 512;
        const float4 vp = *(const float4*)&p[k * D_ + lane * 4];
        const float4 va = *(const float4*)&a[k * D_ + lane * 4];
        ushort4 hp, lp, ha, la;
        split2(vp.x, hp.x, lp.x); split2(vp.y, hp.y, lp.y);
        split2(vp.z, hp.z, lp.z); split2(vp.w, hp.w, lp.w);
        split2(va.x, ha.x, la.x); split2(va.y, ha.y, la.y);
        split2(va.z, ha.z, la.z); split2(va.w, ha.w, la.w);
        *(ushort4*)&wsu[PHI_OFF + k * D_ + lane * 4] = hp;
        *(ushort4*)&wsu[PLO_OFF + k * D_ + lane * 4] = lp;
        *(ushort4*)&wsu[AHI_OFF + k * D_ + lane * 4] = ha;
        *(ushort4*)&wsu[ALO_OFF + k * D_ + lane * 4] = la;
        float sp = vp.x * vp.x + vp.y * vp.y + vp.z * vp.z + vp.w * vp.w;
        float sa = va.x * va.x + va.y * va.y + va.z * va.z + va.w * va.w;
        float sx = vp.x * va.x + vp.y * va.y + vp.z * va.z + vp.w * va.w;
#pragma unroll
        for (int off = 32; off; off >>= 1) {
            sp += __shfl_down(sp, off);
            sa += __shfl_down(sa, off);
            sx += __shfl_down(sx, off);
        }
        if (lane == 0) { p2[k] = sp; a2[k] = sa; pa[k] = sx; }
    }
}

// Ganea hyperbolic MLR logit from the 6 scalars (same algebra as the verified
// round-1 kernel: z never materialized).
__device__ inline float hyp_logit(float dt, float xa, float x2,
                                  float p2, float a2, float pav) {
    const float beta  = 1.0f - p2;
    const float alpha = 1.0f + x2 - 2.0f * dt;
    const float den   = 1.0f - 2.0f * dt + p2 * x2;
    const float rg    = 1.0f / (den + EPS_);
    const float z2    = (alpha * alpha * p2 - 2.0f * alpha * beta * dt
                         + beta * beta * x2) * rg * rg;
    const float za    = beta * (beta * xa - alpha * pav) * rg;
    const float na    = beta * sqrtf(a2);
    const float lam   = 2.0f / (beta + EPS_);
    const float arg   = 2.0f * za / ((1.0f - z2) * na + EPS_);
    return lam * na * asinhf(arg);
}

// ---------------------------------------------------------------------------
// Kernel 2: dual GEMM via mfma_f32_16x16x32_bf16, 3-pass hi/lo split
// (hi*hi + hi*lo + lo*hi), fragments loaded straight from L2 (no LDS).
// Per wave: 16 b-rows x 32 k-cols, full D. A-frag: X[b0+(lane&15)][quad*8+j];
// B-frag: P/A[kc+(lane&15)][quad*8+j]. C/D: col=lane&15, row=quad*4+reg
// (HW-verified layout).
// Grid (8, 32) x 256 threads: block = 16 b x 128 k, wave w gets k-sub w*32.
// ---------------------------------------------------------------------------
__global__ __launch_bounds__(256) void mfma_kernel(
    const u16* __restrict__ wsu, const float* __restrict__ scal,
    float* __restrict__ out)
{
    const int lane = threadIdx.x & 63;
    const int w    = threadIdx.x >> 6;
    const int l15  = lane & 15;
    const int quad = lane >> 4;
    const int b0   = blockIdx.y * 16;
    const int kw   = blockIdx.x * 128 + w * 32;

    const u16* xhi = wsu + XHI_OFF;
    const u16* xlo = wsu + XLO_OFF;
    const u16* phi = wsu + PHI_OFF;
    const u16* plo = wsu + PLO_OFF;
    const u16* ahi = wsu + AHI_OFF;
    const u16* alo = wsu + ALO_OFF;
    const float* x2s = scal;
    const float* p2s = scal + 512;
    const float* a2s = scal + 512 + 1024;
    const float* pas = scal + 512 + 2048;

    const int arow = b0 + l15;
    const int kc0  = kw + l15;
    const int kc1  = kw + 16 + l15;
    const int dq   = quad * 8;

    const u16* xh  = xhi + arow * D_ + dq;
    const u16* xl  = xlo + arow * D_ + dq;
    const u16* p0h = phi + kc0 * D_ + dq;
    const u16* p0l = plo + kc0 * D_ + dq;
    const u16* a0h = ahi + kc0 * D_ + dq;
    const u16* a0l = alo + kc0 * D_ + dq;
    const u16* p1h = phi + kc1 * D_ + dq;
    const u16* p1l = plo + kc1 * D_ + dq;
    const u16* a1h = ahi + kc1 * D_ + dq;
    const u16* a1l = alo + kc1 * D_ + dq;

    f32x4 accP0 = {0.f, 0.f, 0.f, 0.f};
    f32x4 accA0 = {0.f, 0.f, 0.f, 0.f};
    f32x4 accP1 = {0.f, 0.f, 0.f, 0.f};
    f32x4 accA1 = {0.f, 0.f, 0.f, 0.f};

#pragma unroll
    for (int dc = 0; dc < 8; ++dc) {
        const int d = dc * 32;
        bf16x8 Ah  = *(const bf16x8*)(xh + d);
        bf16x8 Al  = *(const bf16x8*)(xl + d);
        bf16x8 P0h = *(const bf16x8*)(p0h + d);
        bf16x8 P0l = *(const bf16x8*)(p0l + d);
        bf16x8 B0h = *(const bf16x8*)(a0h + d);
        bf16x8 B0l = *(const bf16x8*)(a0l + d);
        bf16x8 P1h = *(const bf16x8*)(p1h + d);
        bf16x8 P1l = *(const bf16x8*)(p1l + d);
        bf16x8 B1h = *(const bf16x8*)(a1h + d);
        bf16x8 B1l = *(const bf16x8*)(a1l + d);

        accP0 = __builtin_amdgcn_mfma_f32_16x16x32_bf16(Ah, P0h, accP0, 0, 0, 0);
        accP0 = __builtin_amdgcn_mfma_f32_16x16x32_bf16(Ah, P0l, accP0, 0, 0, 0);
        accP0 = __builtin_amdgcn_mfma_f32_16x16x32_bf16(Al, P0h, accP0, 0, 0, 0);

        accA0 = __builtin_amdgcn_mfma_f32_16x16x32_bf16(Ah, B0h, accA0, 0, 0, 0);
        accA0 = __builtin_amdgcn_mfma_f32_16x16x32_bf16(Ah, B0l, accA0, 0, 0, 0);
        accA0 = __builtin_amdgcn_mfma_f32_16x16x32_bf16(Al, B0h, accA0, 0, 0, 0);

        accP1 = __builtin_amdgcn_mfma_f32_16x16x32_bf16(Ah, P1h, accP1, 0, 0, 0);
        accP1 = __builtin_amdgcn_mfma_f32_16x16x32_bf16(Ah, P1l, accP1, 0, 0, 0);
        accP1 = __builtin_amdgcn_mfma_f32_16x16x32_bf16(Al, P1h, accP1, 0, 0, 0);

        accA1 = __builtin_amdgcn_mfma_f32_16x16x32_bf16(Ah, B1h, accA1, 0, 0, 0);
        accA1 = __builtin_amdgcn_mfma_f32_16x16x32_bf16(Ah, B1l, accA1, 0, 0, 0);
        accA1 = __builtin_amdgcn_mfma_f32_16x16x32_bf16(Al, B1h, accA1, 0, 0, 0);
    }

    const float p2v0 = p2s[kc0], a2v0 = a2s[kc0], pav0 = pas[kc0];
    const float p2v1 = p2s[kc1], a2v1 = a2s[kc1], pav1 = pas[kc1];
#pragma unroll
    for (int r = 0; r < 4; ++r) {
        const int b = b0 + quad * 4 + r;
        const float x2v = x2s[b];
        out[b * K_ + kc0] = hyp_logit(accP0[r], accA0[r], x2v, p2v0, a2v0, pav0);
        out[b * K_ + kc1] = hyp_logit(accP1[r], accA1[r], x2v, p2v1, a2v1, pav1);
    }
}

extern "C" void kernel_launch(void* const* d_in, const int* in_sizes, int n_in,
                              void* d_out, int out_size, void* d_ws, size_t ws_size,
                              hipStream_t stream) {
    const float* x = (const float*)d_in[0];  // [512, 256]
    const float* p = (const float*)d_in[1];  // [1024, 256]
    const float* a = (const float*)d_in[2];  // [1024, 256]
    float* out = (float*)d_out;              // [512, 1024]
    u16* wsu   = (u16*)d_ws;
    float* scal = (float*)((char*)d_ws + SCAL_BYTE_OFF);

    prep_kernel<<<384, 256, 0, stream>>>(x, p, a, wsu, scal);
    dim3 g2(8, 32);  // 256 blocks: 16b x 128k each
    mfma_kernel<<<g2, 256, 0, stream>>>(wsu, scal, out);
}